// Round 1
// baseline (237.196 us; speedup 1.0000x reference)
//
#include <hip/hip_runtime.h>

// Problem constants (match reference)
#define Bsz 32
#define Csz 256
#define Hsz 64
#define Wsz 64
#define BIN 16

// One thread per output element of output_1; computes output_2 too (same
// coordinates/weights, different feature map). tid -> (b,c,i,j), j fastest,
// so stores are fully coalesced (out flat index == tid).
__global__ __launch_bounds__(256) void roi_feature_kernel(
    const float* __restrict__ orig,
    const float* __restrict__ lab,
    const float* __restrict__ attk,
    float* __restrict__ out)
{
    const int tid = blockIdx.x * blockDim.x + threadIdx.x;
    const int j = tid & (BIN - 1);
    const int i = (tid >> 4) & (BIN - 1);
    const int c = (tid >> 8) & (Csz - 1);
    const int b = tid >> 16;

    // lab[b,0,{1,2,3,4}] — broadcast reads, L1-cached
    const float* lb = lab + b * 5;
    const float l1 = lb[1], l2 = lb[2], l3 = lb[3], l4 = lb[4];

    // grid[...,0] = mesh_y[b,j] (uses lab3/lab1) -> x
    // grid[...,1] = mesh_x[b,i] (uses lab4/lab2) -> y
    const float gx = 2.0f * (float)(j - BIN / 2) * l3 / (float)BIN + (l1 * 2.0f - 1.0f);
    const float gy = 2.0f * (float)(i - BIN / 2) * l4 / (float)BIN + (l2 * 2.0f - 1.0f);

    const float x = ((gx + 1.0f) * (float)Wsz - 1.0f) * 0.5f;
    const float y = ((gy + 1.0f) * (float)Hsz - 1.0f) * 0.5f;

    const float x0f = floorf(x);
    const float y0f = floorf(y);
    const int x0 = (int)x0f;
    const int y0 = (int)y0f;
    const int x1 = x0 + 1;
    const int y1 = y0 + 1;
    const float wx1 = x - x0f, wx0 = 1.0f - wx1;
    const float wy1 = y - y0f, wy0 = 1.0f - wy1;

    const size_t plane = (size_t)(b * Csz + c) * (Hsz * Wsz);
    const float* __restrict__ f0 = orig + plane;
    const float* __restrict__ f1 = attk + plane;

    float acc0 = 0.0f, acc1 = 0.0f;
#pragma unroll
    for (int k = 0; k < 4; ++k) {
        const int xi = (k & 1) ? x1 : x0;
        const int yi = (k & 2) ? y1 : y0;
        const float w = ((k & 1) ? wx1 : wx0) * ((k & 2) ? wy1 : wy0);
        const bool valid = (xi >= 0) && (xi < Wsz) && (yi >= 0) && (yi < Hsz);
        const int xc = min(max(xi, 0), Wsz - 1);
        const int yc = min(max(yi, 0), Hsz - 1);
        const float wv = valid ? w : 0.0f;
        const int off = yc * Wsz + xc;
        acc0 += f0[off] * wv;
        acc1 += f1[off] * wv;
    }

    out[tid] = acc0;
    out[tid + (size_t)Bsz * Csz * BIN * BIN] = acc1;
}

extern "C" void kernel_launch(void* const* d_in, const int* in_sizes, int n_in,
                              void* d_out, int out_size, void* d_ws, size_t ws_size,
                              hipStream_t stream) {
    const float* orig = (const float*)d_in[0];
    const float* lab  = (const float*)d_in[1];
    const float* attk = (const float*)d_in[2];
    float* out = (float*)d_out;

    const int total = Bsz * Csz * BIN * BIN;  // 2,097,152 threads
    roi_feature_kernel<<<total / 256, 256, 0, stream>>>(orig, lab, attk, out);
}